// Round 2
// baseline (316.951 us; speedup 1.0000x reference)
//
#include <hip/hip_runtime.h>
#include <hip/hip_bf16.h>

// RNN wavefunction log-prob: N=128 steps, B=8192, H=128, D=2 (one-hot).
// ALL inputs/outputs are float32 (per reference). One persistent kernel:
// grid 512 x 256 threads, each block owns 16 samples through all 128 steps.
// Weights converted once to bf16 MFMA B-fragments held in VGPRs.
// Hidden state ping-pongs through XOR-swizzled LDS (bf16); accum in f32.

#define NSTEP 128
#define BTOT  8192
#define HID   128
#define MB    16              // samples per block
#define NBLK  (BTOT / MB)     // 512
#define NTHR  256

typedef __attribute__((ext_vector_type(8))) short bf16x8;
typedef __attribute__((ext_vector_type(4))) float f32x4;

__device__ __forceinline__ short f2bf(float v) {
    __hip_bfloat16 h = __float2bfloat16(v);
    return __builtin_bit_cast(short, h);
}
__device__ __forceinline__ float bf2f(short s) {
    unsigned int u = ((unsigned int)(unsigned short)s) << 16;
    return __builtin_bit_cast(float, u);
}
__device__ __forceinline__ float fast_tanh(float x) {
    // tanh(x) = 1 - 2/(exp(2x)+1), exp via v_exp_f32 (exp2)
    float e = __builtin_exp2f(x * 2.885390081777927f);     // exp(2x)
    float r = __builtin_amdgcn_rcpf(e + 1.0f);             // v_rcp_f32
    return 1.0f - 2.0f * r;
}

// swizzled LDS halfword index for H element (m, k), m in [0,16), k in [0,128)
__device__ __forceinline__ int hidx(int m, int k) {
    return m * HID + (((k >> 3) ^ m) << 3) + (k & 7);
}

__global__ __launch_bounds__(NTHR, 2) void rnn_wf_kernel(
    const float* __restrict__ samples,  // (128, 8192, 2) f32 one-hot
    const float* __restrict__ Wih0,     // (128, 2)
    const float* __restrict__ bih0,     // (128,)
    const float* __restrict__ Whh0,     // (128, 128)
    const float* __restrict__ bhh0,     // (128,)
    const float* __restrict__ Wih1,     // (128, 128)
    const float* __restrict__ bih1,     // (128,)
    const float* __restrict__ Whh1,     // (128, 128)
    const float* __restrict__ bhh1,     // (128,)
    const float* __restrict__ Wd,       // (2, 128)
    const float* __restrict__ bd,       // (2,)
    float* __restrict__ out)            // (1, 8192) f32
{
    __shared__ short sH0[2][MB * HID];  // 4KB each, ping-pong
    __shared__ short sH1[2][MB * HID];
    __shared__ unsigned int sMask[NSTEP];

    const int tid  = threadIdx.x;
    const int b0   = blockIdx.x * MB;
    const int w    = tid >> 6;          // wave 0..3, owns n in [32w, 32w+32)
    const int lane = tid & 63;
    const int q    = lane >> 4;         // quad 0..3
    const int c    = lane & 15;
    const int nbase = w * 32;

    // ---- init: zero current H buffers ----
    for (int i = tid; i < MB * HID; i += NTHR) {
        sH0[0][i] = 0;
        sH1[0][i] = 0;
    }
    // ---- decode f32 one-hot samples -> per-step 16-bit masks ----
    if (tid < NSTEP) {
        unsigned int msk = 0;
        #pragma unroll
        for (int m = 0; m < MB; ++m) {
            // elem1 of (t=tid, b=b0+m): bit=1 means spin index 1
            float e1 = samples[((size_t)tid * BTOT + b0 + m) * 2 + 1];
            if (e1 > 0.5f) msk |= (1u << m);
        }
        sMask[tid] = msk;
    }

    // ---- convert weights to bf16 B-fragments (persist across all steps) ----
    // out[m][n] = sum_k H[m][k] * W[n][k];  B[k][n] = W[n][k]
    // lane holds n = nbase + nt*16 + c, k = kb*32 + q*8 + j (j=0..7)
    bf16x8 fhh0[2][4], fih1[2][4], fhh1[2][4];
    float bias0[2], bias1[2], w0a[2], w0b[2];
    #pragma unroll
    for (int nt = 0; nt < 2; ++nt) {
        const int nn = nbase + nt * 16 + c;
        #pragma unroll
        for (int kb = 0; kb < 4; ++kb) {
            const int off = nn * HID + kb * 32 + q * 8;
            bf16x8 v0, v1, v2;
            #pragma unroll
            for (int j = 0; j < 8; ++j) {
                v0[j] = f2bf(Whh0[off + j]);
                v1[j] = f2bf(Wih1[off + j]);
                v2[j] = f2bf(Whh1[off + j]);
            }
            fhh0[nt][kb] = v0;
            fih1[nt][kb] = v1;
            fhh1[nt][kb] = v2;
        }
        bias0[nt] = bih0[nn] + bhh0[nn];
        bias1[nt] = bih1[nn] + bhh1[nn];
        w0a[nt] = Wih0[nn * 2 + 0];
        w0b[nt] = Wih0[nn * 2 + 1];
    }
    // ---- dense head weights (f32) for the logits phase ----
    const int mo = tid >> 4;        // sample owned for logits, 0..15
    const int kslot = tid & 15;     // k chunk, 8 wide
    float wd0f[8], wd1f[8];
    #pragma unroll
    for (int j = 0; j < 8; ++j) {
        wd0f[j] = Wd[kslot * 8 + j];
        wd1f[j] = Wd[HID + kslot * 8 + j];
    }
    const float bd0 = bd[0], bd1 = bd[1];

    __syncthreads();

    float lp = 0.0f;
    int cur = 0;

    for (int t = 0; t < NSTEP; ++t) {
        const short* h0c = sH0[cur];
        short*       h0n = sH0[cur ^ 1];
        const short* h1c = sH1[cur];
        short*       h1n = sH1[cur ^ 1];

        // ---- phase A: acc0 = H0 @ Whh0^T ; acc1 = H1 @ Whh1^T ----
        f32x4 acc0[2] = {{0.f,0.f,0.f,0.f},{0.f,0.f,0.f,0.f}};
        f32x4 acc1[2] = {{0.f,0.f,0.f,0.f},{0.f,0.f,0.f,0.f}};
        #pragma unroll
        for (int kb = 0; kb < 4; ++kb) {
            const int aoff = c * HID + (((kb * 4 + q) ^ c) << 3);
            bf16x8 a0 = *reinterpret_cast<const bf16x8*>(&h0c[aoff]);
            acc0[0] = __builtin_amdgcn_mfma_f32_16x16x32_bf16(a0, fhh0[0][kb], acc0[0], 0, 0, 0);
            acc0[1] = __builtin_amdgcn_mfma_f32_16x16x32_bf16(a0, fhh0[1][kb], acc0[1], 0, 0, 0);
            bf16x8 a1 = *reinterpret_cast<const bf16x8*>(&h1c[aoff]);
            acc1[0] = __builtin_amdgcn_mfma_f32_16x16x32_bf16(a1, fhh1[0][kb], acc1[0], 0, 0, 0);
            acc1[1] = __builtin_amdgcn_mfma_f32_16x16x32_bf16(a1, fhh1[1][kb], acc1[1], 0, 0, 0);
        }
        // ---- epilogue 0: + bias + one-hot W_ih0 column, tanh, store h0' ----
        const unsigned int mprev = (t > 0) ? sMask[t - 1] : 0u;
        #pragma unroll
        for (int nt = 0; nt < 2; ++nt) {
            const int nn = nbase + nt * 16 + c;
            #pragma unroll
            for (int r = 0; r < 4; ++r) {
                const int m = q * 4 + r;
                float pre = acc0[nt][r] + bias0[nt];
                if (t > 0)   // uniform branch; x_0 = 0 contributes nothing
                    pre += ((mprev >> m) & 1) ? w0b[nt] : w0a[nt];
                h0n[hidx(m, nn)] = f2bf(fast_tanh(pre));
            }
        }
        __syncthreads();   // B1: h0' visible

        // ---- phase B: acc1 += h0' @ Wih1^T ----
        #pragma unroll
        for (int kb = 0; kb < 4; ++kb) {
            const int aoff = c * HID + (((kb * 4 + q) ^ c) << 3);
            bf16x8 an = *reinterpret_cast<const bf16x8*>(&h0n[aoff]);
            acc1[0] = __builtin_amdgcn_mfma_f32_16x16x32_bf16(an, fih1[0][kb], acc1[0], 0, 0, 0);
            acc1[1] = __builtin_amdgcn_mfma_f32_16x16x32_bf16(an, fih1[1][kb], acc1[1], 0, 0, 0);
        }
        // ---- epilogue 1: + bias, tanh, store h1' ----
        #pragma unroll
        for (int nt = 0; nt < 2; ++nt) {
            const int nn = nbase + nt * 16 + c;
            #pragma unroll
            for (int r = 0; r < 4; ++r) {
                const int m = q * 4 + r;
                h1n[hidx(m, nn)] = f2bf(fast_tanh(acc1[nt][r] + bias1[nt]));
            }
        }
        __syncthreads();   // B2: h1' visible

        // ---- logits + log-softmax (2 classes), accumulate log p ----
        {
            bf16x8 hv = *reinterpret_cast<const bf16x8*>(&h1n[hidx(mo, kslot * 8)]);
            float p0 = 0.f, p1 = 0.f;
            #pragma unroll
            for (int j = 0; j < 8; ++j) {
                const float hf = bf2f(hv[j]);
                p0 = fmaf(wd0f[j], hf, p0);
                p1 = fmaf(wd1f[j], hf, p1);
            }
            #pragma unroll
            for (int s = 1; s < 16; s <<= 1) {
                p0 += __shfl_xor(p0, s, 64);
                p1 += __shfl_xor(p1, s, 64);
            }
            const float l0 = p0 + bd0, l1 = p1 + bd1;
            const int bit = (sMask[t] >> mo) & 1;
            const float lc = bit ? l1 : l0;
            const float lo = bit ? l0 : l1;
            // lp += lc - logsumexp(l0,l1) = -log(1 + exp(lo - lc))
            const float ed = __builtin_exp2f((lo - lc) * 1.4426950408889634f);
            lp -= 0.6931471805599453f * __builtin_log2f(1.0f + ed);
        }
        cur ^= 1;
    }

    if ((tid & 15) == 0)
        out[b0 + mo] = lp;
}

extern "C" void kernel_launch(void* const* d_in, const int* in_sizes, int n_in,
                              void* d_out, int out_size, void* d_ws, size_t ws_size,
                              hipStream_t stream) {
    rnn_wf_kernel<<<NBLK, NTHR, 0, stream>>>(
        (const float*)d_in[0],  // samples
        (const float*)d_in[1],  // W_ih0
        (const float*)d_in[2],  // b_ih0
        (const float*)d_in[3],  // W_hh0
        (const float*)d_in[4],  // b_hh0
        (const float*)d_in[5],  // W_ih1
        (const float*)d_in[6],  // b_ih1
        (const float*)d_in[7],  // W_hh1
        (const float*)d_in[8],  // b_hh1
        (const float*)d_in[9],  // W_dense
        (const float*)d_in[10], // b_dense
        (float*)d_out);
}

// Round 3
// 294.546 us; speedup vs baseline: 1.0761x; 1.0761x over previous
//
#include <hip/hip_runtime.h>
#include <hip/hip_bf16.h>

// RNN wavefunction log-prob: N=128 steps, B=8192, H=128, D=2 (one-hot).
// f32 in/out. Grid 512 x 256; block owns 16 samples for all 128 steps.
// MFMA computes D[n][m] = sum_k W[n][k] h[m][k]  (A=weights, B=hidden^T):
// C-layout gives each lane 4 consecutive n for ONE sample m=lane&15, so
// bias+one-hot-input fold into the accumulator init, stores are packed
// ds_write_b64, and the dense head is one extra MFMA (no shuffles).

#define NSTEP 128
#define BTOT  8192
#define HID   128
#define MB    16
#define NBLK  (BTOT / MB)   // 512
#define NTHR  256

typedef __attribute__((ext_vector_type(8))) short bf16x8;
typedef __attribute__((ext_vector_type(4))) float f32x4;

__device__ __forceinline__ short f2bf(float v) {
    unsigned u = __builtin_bit_cast(unsigned, v);
    u += 0x7FFFu + ((u >> 16) & 1u);          // RNE (inputs never NaN)
    return (short)(u >> 16);
}
__device__ __forceinline__ unsigned pk2bf(float a, float b) {
    unsigned ua = __builtin_bit_cast(unsigned, a);
    unsigned ub = __builtin_bit_cast(unsigned, b);
    ua += 0x7FFFu + ((ua >> 16) & 1u);
    ub += 0x7FFFu + ((ub >> 16) & 1u);
    return (ua >> 16) | (ub & 0xFFFF0000u);
}
__device__ __forceinline__ float fast_tanh(float x) {
    float e = __builtin_exp2f(x * 2.885390081777927f);   // exp(2x)
    float r = __builtin_amdgcn_rcpf(e + 1.0f);
    return 1.0f - 2.0f * r;
}

__global__ __launch_bounds__(NTHR, 2) void rnn_wf_kernel(
    const float* __restrict__ samples,  // (128, 8192, 2)
    const float* __restrict__ Wih0,     // (128, 2)
    const float* __restrict__ bih0,     // (128,)
    const float* __restrict__ Whh0,     // (128, 128)
    const float* __restrict__ bhh0,     // (128,)
    const float* __restrict__ Wih1,     // (128, 128)
    const float* __restrict__ bih1,     // (128,)
    const float* __restrict__ Whh1,     // (128, 128)
    const float* __restrict__ bhh1,     // (128,)
    const float* __restrict__ Wd,       // (2, 128)
    const float* __restrict__ bd,       // (2,)
    float* __restrict__ out)            // (1, 8192)
{
    __shared__ short sH0[2][MB * HID];  // h[m][k] rows, 16B-block XOR swizzle
    __shared__ short sH1[2][MB * HID];
    __shared__ unsigned sMask[NSTEP];

    const int tid  = threadIdx.x;
    const int b0   = blockIdx.x * MB;
    const int w    = tid >> 6;
    const int lane = tid & 63;
    const int q    = lane >> 4;
    const int c    = lane & 15;
    const int nb   = w * 32;

    for (int i = tid; i < MB * HID; i += NTHR) {
        sH0[0][i] = 0;
        sH1[0][i] = 0;
    }
    if (tid < NSTEP) {
        unsigned msk = 0;
        #pragma unroll
        for (int m = 0; m < MB; ++m) {
            float e1 = samples[((size_t)tid * BTOT + b0 + m) * 2 + 1];
            if (e1 > 0.5f) msk |= (1u << m);
        }
        sMask[tid] = msk;
    }

    // ---- weight A-fragments: lane holds W[nb+nt*16+c][kb*32+q*8 .. +8] ----
    bf16x8 fhh0[2][4], fih1[2][4], fhh1[2][4];
    #pragma unroll
    for (int nt = 0; nt < 2; ++nt) {
        const int nn = nb + nt * 16 + c;
        #pragma unroll
        for (int kb = 0; kb < 4; ++kb) {
            const int off = nn * HID + kb * 32 + q * 8;
            bf16x8 v0, v1, v2;
            #pragma unroll
            for (int j = 0; j < 8; ++j) {
                v0[j] = f2bf(Whh0[off + j]);
                v1[j] = f2bf(Wih1[off + j]);
                v2[j] = f2bf(Whh1[off + j]);
            }
            fhh0[nt][kb] = v0; fih1[nt][kb] = v1; fhh1[nt][kb] = v2;
        }
    }
    // dense-head A-fragment: rows 0,1 = Wd, rows >=2 zero
    bf16x8 fwd[4];
    #pragma unroll
    for (int kb = 0; kb < 4; ++kb) {
        bf16x8 v;
        #pragma unroll
        for (int j = 0; j < 8; ++j)
            v[j] = (c < 2) ? f2bf(Wd[c * HID + kb * 32 + q * 8 + j]) : (short)0;
        fwd[kb] = v;
    }
    // ---- per-lane constant vectors over (nt, r): n = nb + nt*16 + q*4 + r ----
    float pA[2][4], pB[2][4], b0v[2][4], b1v[2][4];
    #pragma unroll
    for (int nt = 0; nt < 2; ++nt)
        #pragma unroll
        for (int r = 0; r < 4; ++r) {
            const int n = nb + nt * 16 + q * 4 + r;
            const float bb = bih0[n] + bhh0[n];
            b0v[nt][r] = bb;
            pA[nt][r]  = bb + Wih0[n * 2 + 0];
            pB[nt][r]  = bb + Wih0[n * 2 + 1];
            b1v[nt][r] = bih1[n] + bhh1[n];
        }
    const float bd0 = bd[0], bd1 = bd[1];

    // ---- t-invariant LDS addresses (halfword units) ----
    // read: B-frag h[m=c][kb*32+q*8 ..+8], block (4kb+q) XOR c
    int ra[4];
    #pragma unroll
    for (int kb = 0; kb < 4; ++kb)
        ra[kb] = c * HID + (((kb * 4 + q) ^ (c & 7)) << 3);
    // write: h[m=c][32w+16nt+4q ..+4]; block 4w+2nt+(q>>1), half-block q&1
    int wa[2];
    #pragma unroll
    for (int nt = 0; nt < 2; ++nt)
        wa[nt] = c * HID + ((((w << 2) + (nt << 1) + (q >> 1)) ^ (c & 7)) << 3)
               + ((q & 1) << 2);

    __syncthreads();

    float lp = 0.0f;
    int cur = 0;

    for (int t = 0; t < NSTEP; ++t) {
        const short* h0c = sH0[cur];
        short*       h0n = sH0[cur ^ 1];
        const short* h1c = sH1[cur];
        short*       h1n = sH1[cur ^ 1];

        const unsigned mPrev = (t > 0) ? sMask[t - 1] : 0u;
        const bool bm = (mPrev >> c) & 1u;   // spin s_{t-1} of this lane's sample
        const bool first = (t == 0);

        // ---- acc init: bias (+ one-hot W_ih0 column) pre-folded ----
        f32x4 acc0[2], acc1[2], accL = {0.f, 0.f, 0.f, 0.f};
        #pragma unroll
        for (int nt = 0; nt < 2; ++nt)
            #pragma unroll
            for (int r = 0; r < 4; ++r) {
                acc0[nt][r] = first ? b0v[nt][r] : (bm ? pB[nt][r] : pA[nt][r]);
                acc1[nt][r] = b1v[nt][r];
            }

        // ---- phase A: Whh0@h0, Whh1@h1, Wd@h1 (logits_{t-1}) ----
        #pragma unroll
        for (int kb = 0; kb < 4; ++kb) {
            bf16x8 b0f = *reinterpret_cast<const bf16x8*>(&h0c[ra[kb]]);
            bf16x8 b1f = *reinterpret_cast<const bf16x8*>(&h1c[ra[kb]]);
            acc0[0] = __builtin_amdgcn_mfma_f32_16x16x32_bf16(fhh0[0][kb], b0f, acc0[0], 0, 0, 0);
            acc0[1] = __builtin_amdgcn_mfma_f32_16x16x32_bf16(fhh0[1][kb], b0f, acc0[1], 0, 0, 0);
            acc1[0] = __builtin_amdgcn_mfma_f32_16x16x32_bf16(fhh1[0][kb], b1f, acc1[0], 0, 0, 0);
            acc1[1] = __builtin_amdgcn_mfma_f32_16x16x32_bf16(fhh1[1][kb], b1f, acc1[1], 0, 0, 0);
            accL    = __builtin_amdgcn_mfma_f32_16x16x32_bf16(fwd[kb],     b1f, accL,    0, 0, 0);
        }

        // ---- logits_{t-1} log-softmax (valid in q==0 lanes; uniform code) ----
        if (t > 0) {
            const float l0 = accL[0] + bd0, l1 = accL[1] + bd1;
            const float lc = bm ? l1 : l0;
            const float lo = bm ? l0 : l1;
            const float ed = __builtin_exp2f((lo - lc) * 1.4426950408889634f);
            lp -= 0.6931471805599453f * __builtin_log2f(1.0f + ed);
        }

        // ---- epilogue 0: tanh, pack 4 consecutive n, one b64 store per nt ----
        #pragma unroll
        for (int nt = 0; nt < 2; ++nt) {
            const float t0 = fast_tanh(acc0[nt][0]);
            const float t1 = fast_tanh(acc0[nt][1]);
            const float t2 = fast_tanh(acc0[nt][2]);
            const float t3 = fast_tanh(acc0[nt][3]);
            const unsigned long long v =
                (unsigned long long)pk2bf(t0, t1) |
                ((unsigned long long)pk2bf(t2, t3) << 32);
            *reinterpret_cast<unsigned long long*>(&h0n[wa[nt]]) = v;
        }
        __syncthreads();   // B1: h0' visible

        // ---- phase B: Wih1@h0' ----
        #pragma unroll
        for (int kb = 0; kb < 4; ++kb) {
            bf16x8 bnf = *reinterpret_cast<const bf16x8*>(&h0n[ra[kb]]);
            acc1[0] = __builtin_amdgcn_mfma_f32_16x16x32_bf16(fih1[0][kb], bnf, acc1[0], 0, 0, 0);
            acc1[1] = __builtin_amdgcn_mfma_f32_16x16x32_bf16(fih1[1][kb], bnf, acc1[1], 0, 0, 0);
        }
        // ---- epilogue 1 ----
        #pragma unroll
        for (int nt = 0; nt < 2; ++nt) {
            const float t0 = fast_tanh(acc1[nt][0]);
            const float t1 = fast_tanh(acc1[nt][1]);
            const float t2 = fast_tanh(acc1[nt][2]);
            const float t3 = fast_tanh(acc1[nt][3]);
            const unsigned long long v =
                (unsigned long long)pk2bf(t0, t1) |
                ((unsigned long long)pk2bf(t2, t3) << 32);
            *reinterpret_cast<unsigned long long*>(&h1n[wa[nt]]) = v;
        }
        __syncthreads();   // B2: h1' visible

        cur ^= 1;
    }

    // ---- final logits for t = NSTEP-1 from h1^{NSTEP} ----
    {
        const short* h1f = sH1[cur];
        f32x4 accF = {0.f, 0.f, 0.f, 0.f};
        #pragma unroll
        for (int kb = 0; kb < 4; ++kb) {
            bf16x8 b1f = *reinterpret_cast<const bf16x8*>(&h1f[ra[kb]]);
            accF = __builtin_amdgcn_mfma_f32_16x16x32_bf16(fwd[kb], b1f, accF, 0, 0, 0);
        }
        const bool bm = (sMask[NSTEP - 1] >> c) & 1u;
        const float l0 = accF[0] + bd0, l1 = accF[1] + bd1;
        const float lc = bm ? l1 : l0;
        const float lo = bm ? l0 : l1;
        const float ed = __builtin_exp2f((lo - lc) * 1.4426950408889634f);
        lp -= 0.6931471805599453f * __builtin_log2f(1.0f + ed);
    }

    if (tid < 16)
        out[b0 + tid] = lp;
}

extern "C" void kernel_launch(void* const* d_in, const int* in_sizes, int n_in,
                              void* d_out, int out_size, void* d_ws, size_t ws_size,
                              hipStream_t stream) {
    rnn_wf_kernel<<<NBLK, NTHR, 0, stream>>>(
        (const float*)d_in[0],  // samples
        (const float*)d_in[1],  // W_ih0
        (const float*)d_in[2],  // b_ih0
        (const float*)d_in[3],  // W_hh0
        (const float*)d_in[4],  // b_hh0
        (const float*)d_in[5],  // W_ih1
        (const float*)d_in[6],  // b_ih1
        (const float*)d_in[7],  // W_hh1
        (const float*)d_in[8],  // b_hh1
        (const float*)d_in[9],  // W_dense
        (const float*)d_in[10], // b_dense
        (float*)d_out);
}

// Round 5
// 263.190 us; speedup vs baseline: 1.2043x; 1.1191x over previous
//
#include <hip/hip_runtime.h>
#include <hip/hip_bf16.h>

// RNN wavefunction log-prob: N=128 steps, B=8192, H=128, D=2 (one-hot).
// f32 in/out. Grid 512 x 256; block owns 16 samples for all 128 steps.
// Layer-SKEWED pipeline: iteration i computes h0(i), h1(i-1), logits(i-2),
// all from data published at the single barrier of iteration i-1.
// MFMA: D[n][m] = sum_k W[n][k] h[m][k]; weights as A-frags in VGPRs;
// hidden state ping-pongs through LDS with the R2-verified full-c XOR
// swizzle (measured conflict-free). Biases enter as MFMA C-init.

#define NSTEP 128
#define BTOT  8192
#define HID   128
#define MB    16
#define NBLK  (BTOT / MB)   // 512
#define NTHR  256

typedef __attribute__((ext_vector_type(8))) short bf16x8;
typedef __attribute__((ext_vector_type(4))) float f32x4;
typedef __attribute__((ext_vector_type(2))) float f32x2;
typedef __attribute__((ext_vector_type(2))) unsigned uint32x2;

__device__ __forceinline__ short f2bf(float v) {
    unsigned u = __builtin_bit_cast(unsigned, v);
    u += 0x7FFFu + ((u >> 16) & 1u);
    return (short)(u >> 16);
}
// pack two f32 -> two bf16 (RNE); plain integer ops, compiles everywhere
__device__ __forceinline__ unsigned pk2bf(float a, float b) {
    unsigned ua = __builtin_bit_cast(unsigned, a);
    unsigned ub = __builtin_bit_cast(unsigned, b);
    ua += 0x7FFFu + ((ua >> 16) & 1u);
    ub += 0x7FFFu + ((ub >> 16) & 1u);
    return (ua >> 16) | (ub & 0xFFFF0000u);
}
// tanh on a pair; mul/add/fma pack to v_pk_*, exp2/rcp scalar (trans pipe)
__device__ __forceinline__ f32x2 tanh2(f32x2 x) {
    f32x2 z = x * 2.885390081777927f;            // 2x * log2(e) -> exp(2x)
    f32x2 e;
    e.x = __builtin_exp2f(z.x);
    e.y = __builtin_exp2f(z.y);
    f32x2 d = e + 1.0f;
    f32x2 r;
    r.x = __builtin_amdgcn_rcpf(d.x);
    r.y = __builtin_amdgcn_rcpf(d.y);
    return r * -2.0f + 1.0f;                     // v_pk_fma
}

__global__ __launch_bounds__(NTHR, 2) void rnn_wf_kernel(
    const float* __restrict__ samples,  // (128, 8192, 2)
    const float* __restrict__ Wih0,     // (128, 2)
    const float* __restrict__ bih0,     // (128,)
    const float* __restrict__ Whh0,     // (128, 128)
    const float* __restrict__ bhh0,     // (128,)
    const float* __restrict__ Wih1,     // (128, 128)
    const float* __restrict__ bih1,     // (128,)
    const float* __restrict__ Whh1,     // (128, 128)
    const float* __restrict__ bhh1,     // (128,)
    const float* __restrict__ Wd,       // (2, 128)
    const float* __restrict__ bd,       // (2,)
    float* __restrict__ out)            // (1, 8192)
{
    __shared__ short sH0[2][MB * HID];
    __shared__ short sH1[2][MB * HID];
    __shared__ unsigned sMask[NSTEP];

    const int tid  = threadIdx.x;
    const int b0   = blockIdx.x * MB;
    const int w    = tid >> 6;
    const int lane = tid & 63;
    const int q    = lane >> 4;
    const int c    = lane & 15;
    const int nb   = w * 32;

    // ---- decode f32 one-hot samples -> per-step 16-bit masks ----
    if (tid < NSTEP) {
        unsigned msk = 0;
        #pragma unroll
        for (int m = 0; m < MB; ++m) {
            float e1 = samples[((size_t)tid * BTOT + b0 + m) * 2 + 1];
            if (e1 > 0.5f) msk |= (1u << m);
        }
        sMask[tid] = msk;
    }

    // ---- weight A-fragments: lane holds W[nb+nt*16+c][kb*32+q*8 .. +8] ----
    bf16x8 fhh0[2][4], fih1[2][4], fhh1[2][4];
    #pragma unroll
    for (int nt = 0; nt < 2; ++nt) {
        const int nn = nb + nt * 16 + c;
        #pragma unroll
        for (int kb = 0; kb < 4; ++kb) {
            const int off = nn * HID + kb * 32 + q * 8;
            bf16x8 v0, v1, v2;
            #pragma unroll
            for (int j = 0; j < 8; ++j) {
                v0[j] = f2bf(Whh0[off + j]);
                v1[j] = f2bf(Wih1[off + j]);
                v2[j] = f2bf(Whh1[off + j]);
            }
            fhh0[nt][kb] = v0; fih1[nt][kb] = v1; fhh1[nt][kb] = v2;
        }
    }
    bf16x8 fwd[4];                 // dense head rows 0,1; rows>=2 zero
    #pragma unroll
    for (int kb = 0; kb < 4; ++kb) {
        bf16x8 v;
        #pragma unroll
        for (int j = 0; j < 8; ++j)
            v[j] = (c < 2) ? f2bf(Wd[c * HID + kb * 32 + q * 8 + j]) : (short)0;
        fwd[kb] = v;
    }
    // per-lane bias/init vectors over r: n = nb + nt*16 + q*4 + r
    f32x4 pA0, pA1, pB0, pB1, b0v0, b0v1, b1v0, b1v1;
    #pragma unroll
    for (int r = 0; r < 4; ++r) {
        const int n0 = nb + q * 4 + r;
        const int n1 = n0 + 16;
        const float bb0 = bih0[n0] + bhh0[n0];
        const float bb1 = bih0[n1] + bhh0[n1];
        b0v0[r] = bb0;                    b0v1[r] = bb1;
        pA0[r] = bb0 + Wih0[n0 * 2 + 0];  pA1[r] = bb1 + Wih0[n1 * 2 + 0];
        pB0[r] = bb0 + Wih0[n0 * 2 + 1];  pB1[r] = bb1 + Wih0[n1 * 2 + 1];
        b1v0[r] = bih1[n0] + bhh1[n0];    b1v1[r] = bih1[n1] + bhh1[n1];
    }
    const f32x4 bdv = {bd[0], bd[1], 0.f, 0.f};

    // ---- t-invariant LDS addresses (halfword units), full-c XOR swizzle ----
    int ra[4];
    #pragma unroll
    for (int kb = 0; kb < 4; ++kb)
        ra[kb] = c * HID + (((kb * 4 + q) ^ c) << 3);
    int wa0 = c * HID + (((4 * w + (q >> 1)) ^ c) << 3) + ((q & 1) << 2);
    int wa1 = c * HID + (((4 * w + 2 + (q >> 1)) ^ c) << 3) + ((q & 1) << 2);

    float lp = 0.0f;
    bool bmPrev = false;   // bit(i-1) carried to next iteration as bit(i-2)

    auto storeH = [&](short* buf, const f32x4& a0, const f32x4& a1) {
        f32x2 t00 = tanh2((f32x2){a0[0], a0[1]});
        f32x2 t01 = tanh2((f32x2){a0[2], a0[3]});
        f32x2 t10 = tanh2((f32x2){a1[0], a1[1]});
        f32x2 t11 = tanh2((f32x2){a1[2], a1[3]});
        uint32x2 v0 = {pk2bf(t00.x, t00.y), pk2bf(t01.x, t01.y)};
        uint32x2 v1 = {pk2bf(t10.x, t10.y), pk2bf(t11.x, t11.y)};
        *reinterpret_cast<uint32x2*>(&buf[wa0]) = v0;
        *reinterpret_cast<uint32x2*>(&buf[wa1]) = v1;
    };
    auto lpAdd = [&](const f32x4& aL, bool bit) {
        const float l0 = aL[0], l1 = aL[1];
        const float lc = bit ? l1 : l0;
        const float lo = bit ? l0 : l1;
        const float ed = __builtin_exp2f((lo - lc) * 1.4426950408889634f);
        lp -= 0.6931471805599453f * __builtin_log2f(1.0f + ed);
    };

    // ---- i = 0: h0(0) = tanh(b0) ; no reads ----
    __syncthreads();                       // sMask published
    storeH(sH0[1], b0v0, b0v1);
    __syncthreads();

    // ---- i = 1: h0(1), h1(0) ----
    {
        const bool bmIn = (sMask[0] >> c) & 1u;
        bf16x8 f0[4];
        #pragma unroll
        for (int kb = 0; kb < 4; ++kb)
            f0[kb] = *reinterpret_cast<const bf16x8*>(&sH0[1][ra[kb]]);
        f32x4 a00 = bmIn ? pB0 : pA0;
        f32x4 a01 = bmIn ? pB1 : pA1;
        f32x4 a10 = b1v0, a11 = b1v1;
        #pragma unroll
        for (int kb = 0; kb < 4; ++kb) {
            a00 = __builtin_amdgcn_mfma_f32_16x16x32_bf16(fhh0[0][kb], f0[kb], a00, 0, 0, 0);
            a01 = __builtin_amdgcn_mfma_f32_16x16x32_bf16(fhh0[1][kb], f0[kb], a01, 0, 0, 0);
            a10 = __builtin_amdgcn_mfma_f32_16x16x32_bf16(fih1[0][kb], f0[kb], a10, 0, 0, 0);
            a11 = __builtin_amdgcn_mfma_f32_16x16x32_bf16(fih1[1][kb], f0[kb], a11, 0, 0, 0);
        }
        storeH(sH0[0], a00, a01);   // h0(1)
        storeH(sH1[0], a10, a11);   // h1(0)
        bmPrev = bmIn;
        __syncthreads();
    }

    // ---- main: i = 2..127, one barrier per iteration ----
    auto stepMain = [&](int i, const short* r0, const short* r1,
                        short* w0b, short* w1b) {
        const bool bmIn = (sMask[i - 1] >> c) & 1u;
        bf16x8 f0[4], f1[4];
        #pragma unroll
        for (int kb = 0; kb < 4; ++kb) {
            f0[kb] = *reinterpret_cast<const bf16x8*>(&r0[ra[kb]]);
            f1[kb] = *reinterpret_cast<const bf16x8*>(&r1[ra[kb]]);
        }
        f32x4 a00 = bmIn ? pB0 : pA0;       // h0(i) pre-act init
        f32x4 a01 = bmIn ? pB1 : pA1;
        f32x4 a10 = b1v0, a11 = b1v1;       // h1(i-1) pre-act init
        f32x4 aL  = bdv;                    // logits(i-2) init
        #pragma unroll
        for (int kb = 0; kb < 4; ++kb) {
            a00 = __builtin_amdgcn_mfma_f32_16x16x32_bf16(fhh0[0][kb], f0[kb], a00, 0, 0, 0);
            a01 = __builtin_amdgcn_mfma_f32_16x16x32_bf16(fhh0[1][kb], f0[kb], a01, 0, 0, 0);
            a10 = __builtin_amdgcn_mfma_f32_16x16x32_bf16(fhh1[0][kb], f1[kb], a10, 0, 0, 0);
            a11 = __builtin_amdgcn_mfma_f32_16x16x32_bf16(fhh1[1][kb], f1[kb], a11, 0, 0, 0);
            aL  = __builtin_amdgcn_mfma_f32_16x16x32_bf16(fwd[kb],     f1[kb], aL,  0, 0, 0);
        }
        #pragma unroll
        for (int kb = 0; kb < 4; ++kb) {
            a10 = __builtin_amdgcn_mfma_f32_16x16x32_bf16(fih1[0][kb], f0[kb], a10, 0, 0, 0);
            a11 = __builtin_amdgcn_mfma_f32_16x16x32_bf16(fih1[1][kb], f0[kb], a11, 0, 0, 0);
        }
        lpAdd(aL, bmPrev);                  // logits(i-2)
        bmPrev = bmIn;
        storeH(w0b, a00, a01);              // h0(i)
        storeH(w1b, a10, a11);              // h1(i-1)
        __syncthreads();
    };

    for (int i = 2; i < NSTEP; i += 2) {
        stepMain(i,     sH0[0], sH1[0], sH0[1], sH1[1]);
        stepMain(i + 1, sH0[1], sH1[1], sH0[0], sH1[0]);
    }

    // ---- i = 128: h1(127), logits(126) ----
    {
        bf16x8 f0[4], f1[4];
        #pragma unroll
        for (int kb = 0; kb < 4; ++kb) {
            f0[kb] = *reinterpret_cast<const bf16x8*>(&sH0[0][ra[kb]]);  // h0(127)
            f1[kb] = *reinterpret_cast<const bf16x8*>(&sH1[0][ra[kb]]);  // h1(126)
        }
        f32x4 a10 = b1v0, a11 = b1v1;
        f32x4 aL  = bdv;
        #pragma unroll
        for (int kb = 0; kb < 4; ++kb) {
            a10 = __builtin_amdgcn_mfma_f32_16x16x32_bf16(fhh1[0][kb], f1[kb], a10, 0, 0, 0);
            a11 = __builtin_amdgcn_mfma_f32_16x16x32_bf16(fhh1[1][kb], f1[kb], a11, 0, 0, 0);
            aL  = __builtin_amdgcn_mfma_f32_16x16x32_bf16(fwd[kb],     f1[kb], aL,  0, 0, 0);
        }
        #pragma unroll
        for (int kb = 0; kb < 4; ++kb) {
            a10 = __builtin_amdgcn_mfma_f32_16x16x32_bf16(fih1[0][kb], f0[kb], a10, 0, 0, 0);
            a11 = __builtin_amdgcn_mfma_f32_16x16x32_bf16(fih1[1][kb], f0[kb], a11, 0, 0, 0);
        }
        lpAdd(aL, bmPrev);                  // logits(126)
        storeH(sH1[1], a10, a11);           // h1(127)
        __syncthreads();
    }
    // ---- i = 129: logits(127) ----
    {
        f32x4 aL = bdv;
        #pragma unroll
        for (int kb = 0; kb < 4; ++kb) {
            bf16x8 f1 = *reinterpret_cast<const bf16x8*>(&sH1[1][ra[kb]]);
            aL = __builtin_amdgcn_mfma_f32_16x16x32_bf16(fwd[kb], f1, aL, 0, 0, 0);
        }
        lpAdd(aL, (sMask[NSTEP - 1] >> c) & 1u);
    }

    if (tid < 16)
        out[b0 + tid] = lp;
}

extern "C" void kernel_launch(void* const* d_in, const int* in_sizes, int n_in,
                              void* d_out, int out_size, void* d_ws, size_t ws_size,
                              hipStream_t stream) {
    rnn_wf_kernel<<<NBLK, NTHR, 0, stream>>>(
        (const float*)d_in[0],  // samples
        (const float*)d_in[1],  // W_ih0
        (const float*)d_in[2],  // b_ih0
        (const float*)d_in[3],  // W_hh0
        (const float*)d_in[4],  // b_hh0
        (const float*)d_in[5],  // W_ih1
        (const float*)d_in[6],  // b_ih1
        (const float*)d_in[7],  // W_hh1
        (const float*)d_in[8],  // b_hh1
        (const float*)d_in[9],  // W_dense
        (const float*)d_in[10], // b_dense
        (float*)d_out);
}

// Round 6
// 258.561 us; speedup vs baseline: 1.2258x; 1.0179x over previous
//
#include <hip/hip_runtime.h>
#include <hip/hip_bf16.h>

// RNN wavefunction log-prob: N=128 steps, B=8192, H=128, D=2 (one-hot).
// f32 in/out. Grid 512 x 256; block owns 16 samples for all 128 steps.
// Layer-skewed pipeline (one barrier/iter): iter i computes h0(i), h1(i-1),
// and wave 0 stashes logit-diff(i-2) to LDS; log1pexp deferred to one final
// pass. Weights live in VGPRs as MFMA A-frags; hidden state ping-pongs
// through LDS (full-c XOR swizzle); biases enter as the MFMA C operand.
// bf16 pack via v_cvt_pk_bf16_f32; rcp shared across tanh pairs.

#define NSTEP 128
#define BTOT  8192
#define HID   128
#define MB    16
#define NBLK  (BTOT / MB)   // 512
#define NTHR  256

typedef __attribute__((ext_vector_type(8))) short bf16x8;
typedef __attribute__((ext_vector_type(4))) float f32x4;
typedef __attribute__((ext_vector_type(2))) float f32x2;
typedef __attribute__((ext_vector_type(2))) unsigned uint32x2;

__device__ __forceinline__ short f2bf(float v) {
    unsigned u = __builtin_bit_cast(unsigned, v);
    u += 0x7FFFu + ((u >> 16) & 1u);
    return (short)(u >> 16);
}
// two f32 -> packed bf16x2 via v_cvt_pk_bf16_f32 (memcpy: R4's bit_cast fails)
__device__ __forceinline__ unsigned cvt2bf(float a, float b) {
    __hip_bfloat162 h2 = __float22bfloat162_rn(make_float2(a, b));
    unsigned u; __builtin_memcpy(&u, &h2, sizeof(u));
    return u;
}
// tanh on a pair: 2 exp + ONE rcp (shared via rcp(d0*d1)) + pk ops
__device__ __forceinline__ f32x2 tanh2(f32x2 x) {
    f32x2 z = x * 2.885390081777927f;            // 2x*log2(e)
    float e0 = __builtin_exp2f(z.x);
    float e1 = __builtin_exp2f(z.y);
    f32x2 d = {e0 + 1.0f, e1 + 1.0f};
    float r = __builtin_amdgcn_rcpf(d.x * d.y);
    f32x2 inv = {r * d.y, r * d.x};              // 1/d.x, 1/d.y
    return inv * -2.0f + 1.0f;                   // v_pk_fma
}

__global__ __launch_bounds__(NTHR, 2) void rnn_wf_kernel(
    const float* __restrict__ samples,  // (128, 8192, 2)
    const float* __restrict__ Wih0,     // (128, 2)
    const float* __restrict__ bih0,     // (128,)
    const float* __restrict__ Whh0,     // (128, 128)
    const float* __restrict__ bhh0,     // (128,)
    const float* __restrict__ Wih1,     // (128, 128)
    const float* __restrict__ bih1,     // (128,)
    const float* __restrict__ Whh1,     // (128, 128)
    const float* __restrict__ bhh1,     // (128,)
    const float* __restrict__ Wd,       // (2, 128)
    const float* __restrict__ bd,       // (2,)
    float* __restrict__ out)            // (1, 8192)
{
    __shared__ short sH0[2][MB * HID];
    __shared__ short sH1[2][MB * HID];
    __shared__ unsigned sMask[NSTEP];
    __shared__ float sLd[NSTEP * 17];   // logit diffs, [t*17 + s], pad-17

    const int tid  = threadIdx.x;
    const int b0   = blockIdx.x * MB;
    const int w    = tid >> 6;
    const int lane = tid & 63;
    const int q    = lane >> 4;
    const int c    = lane & 15;
    const int nb   = w * 32;

    if (tid < NSTEP) {
        unsigned msk = 0;
        #pragma unroll
        for (int m = 0; m < MB; ++m) {
            float e1 = samples[((size_t)tid * BTOT + b0 + m) * 2 + 1];
            if (e1 > 0.5f) msk |= (1u << m);
        }
        sMask[tid] = msk;
    }

    // ---- weight A-fragments: lane holds W[nb+nt*16+c][kb*32+q*8 .. +8] ----
    bf16x8 fhh0[2][4], fih1[2][4], fhh1[2][4];
    #pragma unroll
    for (int nt = 0; nt < 2; ++nt) {
        const int nn = nb + nt * 16 + c;
        #pragma unroll
        for (int kb = 0; kb < 4; ++kb) {
            const int off = nn * HID + kb * 32 + q * 8;
            bf16x8 v0, v1, v2;
            #pragma unroll
            for (int j = 0; j < 8; ++j) {
                v0[j] = f2bf(Whh0[off + j]);
                v1[j] = f2bf(Wih1[off + j]);
                v2[j] = f2bf(Whh1[off + j]);
            }
            fhh0[nt][kb] = v0; fih1[nt][kb] = v1; fhh1[nt][kb] = v2;
        }
    }
    bf16x8 fwd[4];                 // dense head rows 0,1; rows>=2 zero
    #pragma unroll
    for (int kb = 0; kb < 4; ++kb) {
        bf16x8 v;
        #pragma unroll
        for (int j = 0; j < 8; ++j)
            v[j] = (c < 2) ? f2bf(Wd[c * HID + kb * 32 + q * 8 + j]) : (short)0;
        fwd[kb] = v;
    }
    // per-lane bias/init vectors over r: n = nb + nt*16 + q*4 + r
    f32x4 pA0, pA1, pB0, pB1, b0v0, b0v1, b1v0, b1v1;
    #pragma unroll
    for (int r = 0; r < 4; ++r) {
        const int n0 = nb + q * 4 + r;
        const int n1 = n0 + 16;
        const float bb0 = bih0[n0] + bhh0[n0];
        const float bb1 = bih0[n1] + bhh0[n1];
        b0v0[r] = bb0;                    b0v1[r] = bb1;
        pA0[r] = bb0 + Wih0[n0 * 2 + 0];  pA1[r] = bb1 + Wih0[n1 * 2 + 0];
        pB0[r] = bb0 + Wih0[n0 * 2 + 1];  pB1[r] = bb1 + Wih0[n1 * 2 + 1];
        b1v0[r] = bih1[n0] + bhh1[n0];    b1v1[r] = bih1[n1] + bhh1[n1];
    }
    const f32x4 bdv = {bd[0], bd[1], 0.f, 0.f};

    // ---- t-invariant LDS addresses (halfwords), full-c XOR swizzle ----
    int ra[4];
    #pragma unroll
    for (int kb = 0; kb < 4; ++kb)
        ra[kb] = c * HID + (((kb * 4 + q) ^ c) << 3);
    const int wa0 = c * HID + (((4 * w + (q >> 1)) ^ c) << 3) + ((q & 1) << 2);
    const int wa1 = c * HID + (((4 * w + 2 + (q >> 1)) ^ c) << 3) + ((q & 1) << 2);

    bool bmPrev = false;

    auto storeH = [&](short* buf, const f32x4& a0, const f32x4& a1) {
        f32x2 t00 = tanh2((f32x2){a0[0], a0[1]});
        f32x2 t01 = tanh2((f32x2){a0[2], a0[3]});
        f32x2 t10 = tanh2((f32x2){a1[0], a1[1]});
        f32x2 t11 = tanh2((f32x2){a1[2], a1[3]});
        uint32x2 v0 = {cvt2bf(t00.x, t00.y), cvt2bf(t01.x, t01.y)};
        uint32x2 v1 = {cvt2bf(t10.x, t10.y), cvt2bf(t11.x, t11.y)};
        *reinterpret_cast<uint32x2*>(&buf[wa0]) = v0;
        *reinterpret_cast<uint32x2*>(&buf[wa1]) = v1;
    };

    // ---- i = 0: h0(0) = tanh(b0) ----
    __syncthreads();                       // sMask published
    storeH(sH0[1], b0v0, b0v1);
    __syncthreads();

    // ---- i = 1: h0(1), h1(0) ----
    {
        const bool bmIn = (sMask[0] >> c) & 1u;
        bf16x8 f0[4];
        #pragma unroll
        for (int kb = 0; kb < 4; ++kb)
            f0[kb] = *reinterpret_cast<const bf16x8*>(&sH0[1][ra[kb]]);
        f32x4 a00 = __builtin_amdgcn_mfma_f32_16x16x32_bf16(fhh0[0][0], f0[0], bmIn ? pB0 : pA0, 0, 0, 0);
        f32x4 a01 = __builtin_amdgcn_mfma_f32_16x16x32_bf16(fhh0[1][0], f0[0], bmIn ? pB1 : pA1, 0, 0, 0);
        f32x4 a10 = __builtin_amdgcn_mfma_f32_16x16x32_bf16(fih1[0][0], f0[0], b1v0, 0, 0, 0);
        f32x4 a11 = __builtin_amdgcn_mfma_f32_16x16x32_bf16(fih1[1][0], f0[0], b1v1, 0, 0, 0);
        #pragma unroll
        for (int kb = 1; kb < 4; ++kb) {
            a00 = __builtin_amdgcn_mfma_f32_16x16x32_bf16(fhh0[0][kb], f0[kb], a00, 0, 0, 0);
            a01 = __builtin_amdgcn_mfma_f32_16x16x32_bf16(fhh0[1][kb], f0[kb], a01, 0, 0, 0);
            a10 = __builtin_amdgcn_mfma_f32_16x16x32_bf16(fih1[0][kb], f0[kb], a10, 0, 0, 0);
            a11 = __builtin_amdgcn_mfma_f32_16x16x32_bf16(fih1[1][kb], f0[kb], a11, 0, 0, 0);
        }
        storeH(sH0[0], a00, a01);   // h0(1)
        storeH(sH1[0], a10, a11);   // h1(0)
        bmPrev = bmIn;
        __syncthreads();
    }

    // ---- main: i = 2..127, one barrier per iteration ----
    auto stepMain = [&](int i, const short* r0, const short* r1,
                        short* w0b, short* w1b) {
        const bool bmIn = (sMask[i - 1] >> c) & 1u;
        bf16x8 f0[4], f1[4];
        #pragma unroll
        for (int kb = 0; kb < 4; ++kb) {
            f0[kb] = *reinterpret_cast<const bf16x8*>(&r0[ra[kb]]);
            f1[kb] = *reinterpret_cast<const bf16x8*>(&r1[ra[kb]]);
        }
        f32x4 a00 = __builtin_amdgcn_mfma_f32_16x16x32_bf16(fhh0[0][0], f0[0], bmIn ? pB0 : pA0, 0, 0, 0);
        f32x4 a01 = __builtin_amdgcn_mfma_f32_16x16x32_bf16(fhh0[1][0], f0[0], bmIn ? pB1 : pA1, 0, 0, 0);
        f32x4 a10 = __builtin_amdgcn_mfma_f32_16x16x32_bf16(fhh1[0][0], f1[0], b1v0, 0, 0, 0);
        f32x4 a11 = __builtin_amdgcn_mfma_f32_16x16x32_bf16(fhh1[1][0], f1[0], b1v1, 0, 0, 0);
        #pragma unroll
        for (int kb = 1; kb < 4; ++kb) {
            a00 = __builtin_amdgcn_mfma_f32_16x16x32_bf16(fhh0[0][kb], f0[kb], a00, 0, 0, 0);
            a01 = __builtin_amdgcn_mfma_f32_16x16x32_bf16(fhh0[1][kb], f0[kb], a01, 0, 0, 0);
            a10 = __builtin_amdgcn_mfma_f32_16x16x32_bf16(fhh1[0][kb], f1[kb], a10, 0, 0, 0);
            a11 = __builtin_amdgcn_mfma_f32_16x16x32_bf16(fhh1[1][kb], f1[kb], a11, 0, 0, 0);
        }
        #pragma unroll
        for (int kb = 0; kb < 4; ++kb) {
            a10 = __builtin_amdgcn_mfma_f32_16x16x32_bf16(fih1[0][kb], f0[kb], a10, 0, 0, 0);
            a11 = __builtin_amdgcn_mfma_f32_16x16x32_bf16(fih1[1][kb], f0[kb], a11, 0, 0, 0);
        }
        if (w == 0) {   // wave-uniform: only wave 0 produces logits(i-2)
            f32x4 aL = __builtin_amdgcn_mfma_f32_16x16x32_bf16(fwd[0], f1[0], bdv, 0, 0, 0);
            #pragma unroll
            for (int kb = 1; kb < 4; ++kb)
                aL = __builtin_amdgcn_mfma_f32_16x16x32_bf16(fwd[kb], f1[kb], aL, 0, 0, 0);
            if (q == 0)   // rows 0,1 of D live in quad 0
                sLd[(i - 2) * 17 + c] = bmPrev ? (aL[0] - aL[1]) : (aL[1] - aL[0]);
        }
        bmPrev = bmIn;
        storeH(w0b, a00, a01);              // h0(i)
        storeH(w1b, a10, a11);              // h1(i-1)
        __syncthreads();
    };

    for (int i = 2; i < NSTEP; i += 2) {
        stepMain(i,     sH0[0], sH1[0], sH0[1], sH1[1]);
        stepMain(i + 1, sH0[1], sH1[1], sH0[0], sH1[0]);
    }

    // ---- i = 128: h1(127), logits(126) ----
    {
        bf16x8 f0[4], f1[4];
        #pragma unroll
        for (int kb = 0; kb < 4; ++kb) {
            f0[kb] = *reinterpret_cast<const bf16x8*>(&sH0[0][ra[kb]]);  // h0(127)
            f1[kb] = *reinterpret_cast<const bf16x8*>(&sH1[0][ra[kb]]);  // h1(126)
        }
        f32x4 a10 = __builtin_amdgcn_mfma_f32_16x16x32_bf16(fhh1[0][0], f1[0], b1v0, 0, 0, 0);
        f32x4 a11 = __builtin_amdgcn_mfma_f32_16x16x32_bf16(fhh1[1][0], f1[0], b1v1, 0, 0, 0);
        #pragma unroll
        for (int kb = 1; kb < 4; ++kb) {
            a10 = __builtin_amdgcn_mfma_f32_16x16x32_bf16(fhh1[0][kb], f1[kb], a10, 0, 0, 0);
            a11 = __builtin_amdgcn_mfma_f32_16x16x32_bf16(fhh1[1][kb], f1[kb], a11, 0, 0, 0);
        }
        #pragma unroll
        for (int kb = 0; kb < 4; ++kb) {
            a10 = __builtin_amdgcn_mfma_f32_16x16x32_bf16(fih1[0][kb], f0[kb], a10, 0, 0, 0);
            a11 = __builtin_amdgcn_mfma_f32_16x16x32_bf16(fih1[1][kb], f0[kb], a11, 0, 0, 0);
        }
        if (w == 0) {
            f32x4 aL = __builtin_amdgcn_mfma_f32_16x16x32_bf16(fwd[0], f1[0], bdv, 0, 0, 0);
            #pragma unroll
            for (int kb = 1; kb < 4; ++kb)
                aL = __builtin_amdgcn_mfma_f32_16x16x32_bf16(fwd[kb], f1[kb], aL, 0, 0, 0);
            if (q == 0)
                sLd[126 * 17 + c] = bmPrev ? (aL[0] - aL[1]) : (aL[1] - aL[0]);
        }
        storeH(sH1[1], a10, a11);           // h1(127)
        __syncthreads();
    }
    // ---- i = 129: logits(127), wave 0 only ----
    if (w == 0) {
        f32x4 aL;
        {
            bf16x8 f1 = *reinterpret_cast<const bf16x8*>(&sH1[1][ra[0]]);
            aL = __builtin_amdgcn_mfma_f32_16x16x32_bf16(fwd[0], f1, bdv, 0, 0, 0);
        }
        #pragma unroll
        for (int kb = 1; kb < 4; ++kb) {
            bf16x8 f1 = *reinterpret_cast<const bf16x8*>(&sH1[1][ra[kb]]);
            aL = __builtin_amdgcn_mfma_f32_16x16x32_bf16(fwd[kb], f1, aL, 0, 0, 0);
        }
        if (q == 0) {
            const bool bit = (sMask[NSTEP - 1] >> c) & 1u;
            sLd[127 * 17 + c] = bit ? (aL[0] - aL[1]) : (aL[1] - aL[0]);
        }
    }
    __syncthreads();

    // ---- final pass: lp(s) = sum_t -log(1 + exp(diff_t)) ----
    {
        const int s = tid >> 4;       // sample 0..15
        const int k = tid & 15;       // step sub-index
        float acc = 0.0f;
        #pragma unroll
        for (int j = 0; j < 8; ++j) {
            const float x = sLd[(j * 16 + k) * 17 + s];
            const float ed = __builtin_exp2f(x * 1.4426950408889634f);
            acc -= 0.6931471805599453f * __builtin_log2f(1.0f + ed);
        }
        #pragma unroll
        for (int off = 1; off < 16; off <<= 1)
            acc += __shfl_xor(acc, off, 64);
        if (k == 0)
            out[b0 + s] = acc;
    }
}

extern "C" void kernel_launch(void* const* d_in, const int* in_sizes, int n_in,
                              void* d_out, int out_size, void* d_ws, size_t ws_size,
                              hipStream_t stream) {
    rnn_wf_kernel<<<NBLK, NTHR, 0, stream>>>(
        (const float*)d_in[0],  // samples
        (const float*)d_in[1],  // W_ih0
        (const float*)d_in[2],  // b_ih0
        (const float*)d_in[3],  // W_hh0
        (const float*)d_in[4],  // b_hh0
        (const float*)d_in[5],  // W_ih1
        (const float*)d_in[6],  // b_ih1
        (const float*)d_in[7],  // W_hh1
        (const float*)d_in[8],  // b_hh1
        (const float*)d_in[9],  // W_dense
        (const float*)d_in[10], // b_dense
        (float*)d_out);
}

// Round 7
// 245.117 us; speedup vs baseline: 1.2931x; 1.0548x over previous
//
#include <hip/hip_runtime.h>
#include <hip/hip_bf16.h>

// RNN wavefunction log-prob: N=128 steps, B=8192, H=128, D=2 (one-hot).
// f32 in/out. Grid 512 x 256; block owns 16 samples for all 128 steps.
// Layer-skewed pipeline, one barrier/iter. Weights (3 HxH matrices) live in
// registers as MFMA A-frags; biases + dense head live in LDS to keep register
// demand under the spill line (R6 post-mortem: 21.5 MB/dispatch of scratch
// spill traffic was the real bottleneck). Logits MFMA rotates across waves.

#define NSTEP 128
#define BTOT  8192
#define HID   128
#define MB    16
#define NBLK  (BTOT / MB)   // 512
#define NTHR  256

typedef __attribute__((ext_vector_type(8))) short bf16x8;
typedef __attribute__((ext_vector_type(4))) float f32x4;
typedef __attribute__((ext_vector_type(2))) float f32x2;
typedef __attribute__((ext_vector_type(2))) unsigned uint32x2;

__device__ __forceinline__ short f2bf(float v) {
    unsigned u = __builtin_bit_cast(unsigned, v);
    u += 0x7FFFu + ((u >> 16) & 1u);
    return (short)(u >> 16);
}
// two f32 -> packed bf16x2 via v_cvt_pk_bf16_f32
__device__ __forceinline__ unsigned cvt2bf(float a, float b) {
    __hip_bfloat162 h2 = __float22bfloat162_rn(make_float2(a, b));
    unsigned u; __builtin_memcpy(&u, &h2, sizeof(u));
    return u;
}
// tanh on a pair: 2 exp + ONE rcp (shared via rcp(d0*d1)) + pk ops
__device__ __forceinline__ f32x2 tanh2(f32x2 x) {
    f32x2 z = x * 2.885390081777927f;            // 2x*log2(e)
    float e0 = __builtin_exp2f(z.x);
    float e1 = __builtin_exp2f(z.y);
    f32x2 d = {e0 + 1.0f, e1 + 1.0f};
    float r = __builtin_amdgcn_rcpf(d.x * d.y);
    f32x2 inv = {r * d.y, r * d.x};              // 1/d.x, 1/d.y
    return inv * -2.0f + 1.0f;                   // v_pk_fma
}

__global__ __launch_bounds__(NTHR, 2) void rnn_wf_kernel(
    const float* __restrict__ samples,  // (128, 8192, 2)
    const float* __restrict__ Wih0,     // (128, 2)
    const float* __restrict__ bih0,     // (128,)
    const float* __restrict__ Whh0,     // (128, 128)
    const float* __restrict__ bhh0,     // (128,)
    const float* __restrict__ Wih1,     // (128, 128)
    const float* __restrict__ bih1,     // (128,)
    const float* __restrict__ Whh1,     // (128, 128)
    const float* __restrict__ bhh1,     // (128,)
    const float* __restrict__ Wd,       // (2, 128)
    const float* __restrict__ bd,       // (2,)
    float* __restrict__ out)            // (1, 8192)
{
    __shared__ short sH0[2][MB * HID];
    __shared__ short sH1[2][MB * HID];
    __shared__ unsigned sMask[NSTEP];
    __shared__ float sLd[NSTEP * 17];            // logit diffs [t*17 + s]
    __shared__ __attribute__((aligned(16))) float sBias[4 * HID];
    // sBias segments: [0:128)=WA (b0+Wih0 col0), [128:256)=WB (col1),
    //                 [256:384)=B1, [384:512)=B0 plain
    __shared__ __attribute__((aligned(16))) short sFwd[4 * 64 * 8];  // dense frags

    const int tid  = threadIdx.x;
    const int b0   = blockIdx.x * MB;
    const int w    = tid >> 6;
    const int lane = tid & 63;
    const int q    = lane >> 4;
    const int c    = lane & 15;
    const int nb   = w * 32;

    // ---- decode f32 one-hot samples -> per-step 16-bit masks ----
    if (tid < NSTEP) {
        unsigned msk = 0;
        #pragma unroll
        for (int m = 0; m < MB; ++m) {
            float e1 = samples[((size_t)tid * BTOT + b0 + m) * 2 + 1];
            if (e1 > 0.5f) msk |= (1u << m);
        }
        sMask[tid] = msk;
    }
    // ---- biases into LDS ----
    if (tid < HID) {
        const float bb = bih0[tid] + bhh0[tid];
        sBias[tid]       = bb + Wih0[tid * 2 + 0];
        sBias[128 + tid] = bb + Wih0[tid * 2 + 1];
        sBias[256 + tid] = bih1[tid] + bhh1[tid];
        sBias[384 + tid] = bb;
    }
    // ---- dense-head fragments into LDS (fragment layout, any wave reads) ----
    {
        const int kb = tid >> 6, l = tid & 63, cc = l & 15, qq = l >> 4;
        bf16x8 v;
        #pragma unroll
        for (int j = 0; j < 8; ++j)
            v[j] = (cc < 2) ? f2bf(Wd[cc * HID + kb * 32 + qq * 8 + j]) : (short)0;
        *reinterpret_cast<bf16x8*>(&sFwd[(kb * 64 + l) * 8]) = v;
    }

    // ---- weight A-fragments: lane holds W[nb+nt*16+c][kb*32+q*8 .. +8] ----
    bf16x8 fhh0[2][4], fih1[2][4], fhh1[2][4];
    #pragma unroll
    for (int nt = 0; nt < 2; ++nt) {
        const int nn = nb + nt * 16 + c;
        #pragma unroll
        for (int kb = 0; kb < 4; ++kb) {
            const int off = nn * HID + kb * 32 + q * 8;
            bf16x8 v0, v1, v2;
            #pragma unroll
            for (int j = 0; j < 8; ++j) {
                v0[j] = f2bf(Whh0[off + j]);
                v1[j] = f2bf(Wih1[off + j]);
                v2[j] = f2bf(Whh1[off + j]);
            }
            fhh0[nt][kb] = v0; fih1[nt][kb] = v1; fhh1[nt][kb] = v2;
        }
    }
    const float bd0 = bd[0], bd1 = bd[1];

    // ---- t-invariant LDS indices ----
    int ra[4];
    #pragma unroll
    for (int kb = 0; kb < 4; ++kb)
        ra[kb] = c * HID + (((kb * 4 + q) ^ c) << 3);
    const int wa0 = c * HID + (((4 * w + (q >> 1)) ^ c) << 3) + ((q & 1) << 2);
    const int wa1 = c * HID + (((4 * w + 2 + (q >> 1)) ^ c) << 3) + ((q & 1) << 2);
    const int ib  = nb + q * 4;     // float index into bias arrays

    bool bmPrev = false;

    auto storeH = [&](short* buf, const f32x4& a0, const f32x4& a1) {
        f32x2 t00 = tanh2((f32x2){a0[0], a0[1]});
        f32x2 t01 = tanh2((f32x2){a0[2], a0[3]});
        f32x2 t10 = tanh2((f32x2){a1[0], a1[1]});
        f32x2 t11 = tanh2((f32x2){a1[2], a1[3]});
        uint32x2 v0 = {cvt2bf(t00.x, t00.y), cvt2bf(t01.x, t01.y)};
        uint32x2 v1 = {cvt2bf(t10.x, t10.y), cvt2bf(t11.x, t11.y)};
        *reinterpret_cast<uint32x2*>(&buf[wa0]) = v0;
        *reinterpret_cast<uint32x2*>(&buf[wa1]) = v1;
    };

    __syncthreads();                 // sMask, sBias, sFwd published

    // ---- i = 0: h0(0) = tanh(b0) ----
    {
        f32x4 c0 = *reinterpret_cast<const f32x4*>(&sBias[384 + ib]);
        f32x4 c1 = *reinterpret_cast<const f32x4*>(&sBias[384 + ib + 16]);
        storeH(sH0[1], c0, c1);
    }
    __syncthreads();

    // ---- i = 1: h0(1), h1(0) ----
    {
        const bool bmIn = (sMask[0] >> c) & 1u;
        const float* bp = bmIn ? (sBias + 128) : sBias;
        f32x4 c00 = *reinterpret_cast<const f32x4*>(&bp[ib]);
        f32x4 c01 = *reinterpret_cast<const f32x4*>(&bp[ib + 16]);
        f32x4 c10 = *reinterpret_cast<const f32x4*>(&sBias[256 + ib]);
        f32x4 c11 = *reinterpret_cast<const f32x4*>(&sBias[256 + ib + 16]);
        bf16x8 f0[4];
        #pragma unroll
        for (int kb = 0; kb < 4; ++kb)
            f0[kb] = *reinterpret_cast<const bf16x8*>(&sH0[1][ra[kb]]);
        f32x4 a00 = c00, a01 = c01, a10 = c10, a11 = c11;
        #pragma unroll
        for (int kb = 0; kb < 4; ++kb) {
            a00 = __builtin_amdgcn_mfma_f32_16x16x32_bf16(fhh0[0][kb], f0[kb], a00, 0, 0, 0);
            a01 = __builtin_amdgcn_mfma_f32_16x16x32_bf16(fhh0[1][kb], f0[kb], a01, 0, 0, 0);
            a10 = __builtin_amdgcn_mfma_f32_16x16x32_bf16(fih1[0][kb], f0[kb], a10, 0, 0, 0);
            a11 = __builtin_amdgcn_mfma_f32_16x16x32_bf16(fih1[1][kb], f0[kb], a11, 0, 0, 0);
        }
        storeH(sH0[0], a00, a01);   // h0(1)
        storeH(sH1[0], a10, a11);   // h1(0)
        bmPrev = bmIn;
        __syncthreads();
    }

    // ---- main: i = 2..127, one barrier per iteration ----
    auto stepMain = [&](int i, const short* r0, const short* r1,
                        short* w0b, short* w1b) {
        const bool bmIn = (sMask[i - 1] >> c) & 1u;
        const float* bp = bmIn ? (sBias + 128) : sBias;
        f32x4 a00 = *reinterpret_cast<const f32x4*>(&bp[ib]);
        f32x4 a01 = *reinterpret_cast<const f32x4*>(&bp[ib + 16]);
        f32x4 a10 = *reinterpret_cast<const f32x4*>(&sBias[256 + ib]);
        f32x4 a11 = *reinterpret_cast<const f32x4*>(&sBias[256 + ib + 16]);
        bf16x8 f0[4], f1[4];
        #pragma unroll
        for (int kb = 0; kb < 4; ++kb) {
            f0[kb] = *reinterpret_cast<const bf16x8*>(&r0[ra[kb]]);
            f1[kb] = *reinterpret_cast<const bf16x8*>(&r1[ra[kb]]);
        }
        #pragma unroll
        for (int kb = 0; kb < 4; ++kb) {
            a00 = __builtin_amdgcn_mfma_f32_16x16x32_bf16(fhh0[0][kb], f0[kb], a00, 0, 0, 0);
            a01 = __builtin_amdgcn_mfma_f32_16x16x32_bf16(fhh0[1][kb], f0[kb], a01, 0, 0, 0);
            a10 = __builtin_amdgcn_mfma_f32_16x16x32_bf16(fhh1[0][kb], f1[kb], a10, 0, 0, 0);
            a11 = __builtin_amdgcn_mfma_f32_16x16x32_bf16(fhh1[1][kb], f1[kb], a11, 0, 0, 0);
        }
        #pragma unroll
        for (int kb = 0; kb < 4; ++kb) {
            a10 = __builtin_amdgcn_mfma_f32_16x16x32_bf16(fih1[0][kb], f0[kb], a10, 0, 0, 0);
            a11 = __builtin_amdgcn_mfma_f32_16x16x32_bf16(fih1[1][kb], f0[kb], a11, 0, 0, 0);
        }
        if (w == (i & 3)) {   // rotate logits duty across waves
            f32x4 aL = {bd0, bd1, 0.f, 0.f};
            #pragma unroll
            for (int kb = 0; kb < 4; ++kb) {
                bf16x8 fw = *reinterpret_cast<const bf16x8*>(&sFwd[(kb * 64 + lane) * 8]);
                aL = __builtin_amdgcn_mfma_f32_16x16x32_bf16(fw, f1[kb], aL, 0, 0, 0);
            }
            if (q == 0)
                sLd[(i - 2) * 17 + c] = bmPrev ? (aL[0] - aL[1]) : (aL[1] - aL[0]);
        }
        bmPrev = bmIn;
        storeH(w0b, a00, a01);              // h0(i)
        storeH(w1b, a10, a11);              // h1(i-1)
        __syncthreads();
    };

    for (int i = 2; i < NSTEP; i += 2) {
        stepMain(i,     sH0[0], sH1[0], sH0[1], sH1[1]);
        stepMain(i + 1, sH0[1], sH1[1], sH0[0], sH1[0]);
    }

    // ---- i = 128: h1(127), logits(126) ----
    {
        f32x4 a10 = *reinterpret_cast<const f32x4*>(&sBias[256 + ib]);
        f32x4 a11 = *reinterpret_cast<const f32x4*>(&sBias[256 + ib + 16]);
        bf16x8 f0[4], f1[4];
        #pragma unroll
        for (int kb = 0; kb < 4; ++kb) {
            f0[kb] = *reinterpret_cast<const bf16x8*>(&sH0[0][ra[kb]]);  // h0(127)
            f1[kb] = *reinterpret_cast<const bf16x8*>(&sH1[0][ra[kb]]);  // h1(126)
        }
        #pragma unroll
        for (int kb = 0; kb < 4; ++kb) {
            a10 = __builtin_amdgcn_mfma_f32_16x16x32_bf16(fhh1[0][kb], f1[kb], a10, 0, 0, 0);
            a11 = __builtin_amdgcn_mfma_f32_16x16x32_bf16(fhh1[1][kb], f1[kb], a11, 0, 0, 0);
        }
        #pragma unroll
        for (int kb = 0; kb < 4; ++kb) {
            a10 = __builtin_amdgcn_mfma_f32_16x16x32_bf16(fih1[0][kb], f0[kb], a10, 0, 0, 0);
            a11 = __builtin_amdgcn_mfma_f32_16x16x32_bf16(fih1[1][kb], f0[kb], a11, 0, 0, 0);
        }
        if (w == 0) {
            f32x4 aL = {bd0, bd1, 0.f, 0.f};
            #pragma unroll
            for (int kb = 0; kb < 4; ++kb) {
                bf16x8 fw = *reinterpret_cast<const bf16x8*>(&sFwd[(kb * 64 + lane) * 8]);
                aL = __builtin_amdgcn_mfma_f32_16x16x32_bf16(fw, f1[kb], aL, 0, 0, 0);
            }
            if (q == 0)
                sLd[126 * 17 + c] = bmPrev ? (aL[0] - aL[1]) : (aL[1] - aL[0]);
        }
        storeH(sH1[1], a10, a11);           // h1(127)
        __syncthreads();
    }
    // ---- i = 129: logits(127), wave 1 ----
    if (w == 1) {
        f32x4 aL = {bd0, bd1, 0.f, 0.f};
        #pragma unroll
        for (int kb = 0; kb < 4; ++kb) {
            bf16x8 f1 = *reinterpret_cast<const bf16x8*>(&sH1[1][ra[kb]]);
            bf16x8 fw = *reinterpret_cast<const bf16x8*>(&sFwd[(kb * 64 + lane) * 8]);
            aL = __builtin_amdgcn_mfma_f32_16x16x32_bf16(fw, f1, aL, 0, 0, 0);
        }
        if (q == 0) {
            const bool bit = (sMask[NSTEP - 1] >> c) & 1u;
            sLd[127 * 17 + c] = bit ? (aL[0] - aL[1]) : (aL[1] - aL[0]);
        }
    }
    __syncthreads();

    // ---- final pass: lp(s) = sum_t -log(1 + exp(diff_t)) ----
    {
        const int s = tid >> 4;       // sample 0..15
        const int k = tid & 15;       // step sub-index
        float acc = 0.0f;
        #pragma unroll
        for (int j = 0; j < 8; ++j) {
            const float x = sLd[(j * 16 + k) * 17 + s];
            const float ed = __builtin_exp2f(x * 1.4426950408889634f);
            acc -= 0.6931471805599453f * __builtin_log2f(1.0f + ed);
        }
        #pragma unroll
        for (int off = 1; off < 16; off <<= 1)
            acc += __shfl_xor(acc, off, 64);
        if (k == 0)
            out[b0 + s] = acc;
    }
}

extern "C" void kernel_launch(void* const* d_in, const int* in_sizes, int n_in,
                              void* d_out, int out_size, void* d_ws, size_t ws_size,
                              hipStream_t stream) {
    rnn_wf_kernel<<<NBLK, NTHR, 0, stream>>>(
        (const float*)d_in[0],  // samples
        (const float*)d_in[1],  // W_ih0
        (const float*)d_in[2],  // b_ih0
        (const float*)d_in[3],  // W_hh0
        (const float*)d_in[4],  // b_hh0
        (const float*)d_in[5],  // W_ih1
        (const float*)d_in[6],  // b_ih1
        (const float*)d_in[7],  // W_hh1
        (const float*)d_in[8],  // b_hh1
        (const float*)d_in[9],  // W_dense
        (const float*)d_in[10], // b_dense
        (float*)d_out);
}

// Round 8
// 238.378 us; speedup vs baseline: 1.3296x; 1.0283x over previous
//
#include <hip/hip_runtime.h>
#include <hip/hip_bf16.h>

// RNN wavefunction log-prob: N=128 steps, B=8192, H=128, D=2 (one-hot).
// f32 in/out. Grid 512 x 512 threads (8 waves); block owns 16 samples.
// n-split 8-way: each wave owns 16 of 128 hidden columns -> weight frags
// take 48 VGPRs, total <128 => 4 waves/SIMD (16 waves/CU) for latency
// hiding (R7 post-mortem: latency/occupancy-bound at 2 waves/SIMD).
// Layer-skewed pipeline, one barrier/iter; biases + dense head in LDS.

#define NSTEP 128
#define BTOT  8192
#define HID   128
#define MB    16
#define NBLK  (BTOT / MB)   // 512
#define NTHR  512

typedef __attribute__((ext_vector_type(8))) short bf16x8;
typedef __attribute__((ext_vector_type(4))) float f32x4;
typedef __attribute__((ext_vector_type(2))) float f32x2;
typedef __attribute__((ext_vector_type(2))) unsigned uint32x2;

__device__ __forceinline__ short f2bf(float v) {
    unsigned u = __builtin_bit_cast(unsigned, v);
    u += 0x7FFFu + ((u >> 16) & 1u);
    return (short)(u >> 16);
}
// two f32 -> packed bf16x2 via v_cvt_pk_bf16_f32
__device__ __forceinline__ unsigned cvt2bf(float a, float b) {
    __hip_bfloat162 h2 = __float22bfloat162_rn(make_float2(a, b));
    unsigned u; __builtin_memcpy(&u, &h2, sizeof(u));
    return u;
}
// tanh on a pair: 2 exp + ONE rcp (shared via rcp(d0*d1))
__device__ __forceinline__ f32x2 tanh2(f32x2 x) {
    f32x2 z = x * 2.885390081777927f;            // 2x*log2(e)
    float e0 = __builtin_exp2f(z.x);
    float e1 = __builtin_exp2f(z.y);
    f32x2 d = {e0 + 1.0f, e1 + 1.0f};
    float r = __builtin_amdgcn_rcpf(d.x * d.y);
    f32x2 inv = {r * d.y, r * d.x};              // 1/d.x, 1/d.y
    return inv * -2.0f + 1.0f;
}

__global__ __launch_bounds__(NTHR, 4) void rnn_wf_kernel(
    const float* __restrict__ samples,  // (128, 8192, 2)
    const float* __restrict__ Wih0,     // (128, 2)
    const float* __restrict__ bih0,     // (128,)
    const float* __restrict__ Whh0,     // (128, 128)
    const float* __restrict__ bhh0,     // (128,)
    const float* __restrict__ Wih1,     // (128, 128)
    const float* __restrict__ bih1,     // (128,)
    const float* __restrict__ Whh1,     // (128, 128)
    const float* __restrict__ bhh1,     // (128,)
    const float* __restrict__ Wd,       // (2, 128)
    const float* __restrict__ bd,       // (2,)
    float* __restrict__ out)            // (1, 8192)
{
    __shared__ short sH0[2][MB * HID];
    __shared__ short sH1[2][MB * HID];
    __shared__ unsigned sMask[NSTEP];
    __shared__ float sLd[NSTEP * 17];            // logit diffs [t*17 + s]
    __shared__ __attribute__((aligned(16))) float sBias[4 * HID];
    // segments: [0:128)=WA (b0+Wih0 col0), [128:256)=WB (col1),
    //           [256:384)=B1, [384:512)=B0 plain
    __shared__ __attribute__((aligned(16))) short sFwd[4 * 64 * 8];

    const int tid  = threadIdx.x;
    const int b0   = blockIdx.x * MB;
    const int w    = tid >> 6;          // wave 0..7, owns n in [16w, 16w+16)
    const int lane = tid & 63;
    const int q    = lane >> 4;
    const int c    = lane & 15;

    // ---- decode f32 one-hot samples -> per-step 16-bit masks ----
    if (tid < NSTEP) {
        unsigned msk = 0;
        #pragma unroll
        for (int m = 0; m < MB; ++m) {
            float e1 = samples[((size_t)tid * BTOT + b0 + m) * 2 + 1];
            if (e1 > 0.5f) msk |= (1u << m);
        }
        sMask[tid] = msk;
    }
    // ---- biases into LDS ----
    if (tid >= NSTEP && tid < NSTEP + HID) {
        const int n = tid - NSTEP;
        const float bb = bih0[n] + bhh0[n];
        sBias[n]       = bb + Wih0[n * 2 + 0];
        sBias[128 + n] = bb + Wih0[n * 2 + 1];
        sBias[256 + n] = bih1[n] + bhh1[n];
        sBias[384 + n] = bb;
    }
    // ---- dense-head fragments into LDS ----
    if (tid >= 256 && tid < 512) {
        const int t2 = tid - 256;
        const int kb = t2 >> 6, l = t2 & 63, cc = l & 15, qq = l >> 4;
        bf16x8 v;
        #pragma unroll
        for (int j = 0; j < 8; ++j)
            v[j] = (cc < 2) ? f2bf(Wd[cc * HID + kb * 32 + qq * 8 + j]) : (short)0;
        *reinterpret_cast<bf16x8*>(&sFwd[(kb * 64 + l) * 8]) = v;
    }

    // ---- weight A-fragments: lane holds W[16w+c][kb*32+q*8 .. +8] ----
    bf16x8 fhh0[4], fih1[4], fhh1[4];
    {
        const int nn = w * 16 + c;
        #pragma unroll
        for (int kb = 0; kb < 4; ++kb) {
            const int off = nn * HID + kb * 32 + q * 8;
            bf16x8 v0, v1, v2;
            #pragma unroll
            for (int j = 0; j < 8; ++j) {
                v0[j] = f2bf(Whh0[off + j]);
                v1[j] = f2bf(Wih1[off + j]);
                v2[j] = f2bf(Whh1[off + j]);
            }
            fhh0[kb] = v0; fih1[kb] = v1; fhh1[kb] = v2;
        }
    }
    const float bd0 = bd[0], bd1 = bd[1];

    // ---- t-invariant LDS indices ----
    int ra[4];
    #pragma unroll
    for (int kb = 0; kb < 4; ++kb)
        ra[kb] = c * HID + (((kb * 4 + q) ^ c) << 3);
    // write: h'[m=c][n = 16w + 4q + r]; 8-block = 2w + (q>>1), half q&1
    const int wa = c * HID + (((2 * w + (q >> 1)) ^ c) << 3) + ((q & 1) << 2);
    const int ib = w * 16 + q * 4;   // float index into bias arrays

    bool bmPrev = false;

    // write one layer's 4 tanh'd values (b64)
    auto storeL = [&](short* buf, const f32x4& a) {
        f32x2 t0 = tanh2((f32x2){a[0], a[1]});
        f32x2 t1 = tanh2((f32x2){a[2], a[3]});
        uint32x2 v = {cvt2bf(t0.x, t0.y), cvt2bf(t1.x, t1.y)};
        *reinterpret_cast<uint32x2*>(&buf[wa]) = v;
    };

    __syncthreads();                 // sMask, sBias, sFwd published

    // ---- i = 0: h0(0) = tanh(b0) ----
    storeL(sH0[1], *reinterpret_cast<const f32x4*>(&sBias[384 + ib]));
    __syncthreads();

    // ---- i = 1: h0(1), h1(0) ----
    {
        const bool bmIn = (sMask[0] >> c) & 1u;
        const float* bp = bmIn ? (sBias + 128) : sBias;
        f32x4 a0 = *reinterpret_cast<const f32x4*>(&bp[ib]);
        f32x4 a1 = *reinterpret_cast<const f32x4*>(&sBias[256 + ib]);
        #pragma unroll
        for (int kb = 0; kb < 4; ++kb) {
            bf16x8 f0 = *reinterpret_cast<const bf16x8*>(&sH0[1][ra[kb]]);
            a0 = __builtin_amdgcn_mfma_f32_16x16x32_bf16(fhh0[kb], f0, a0, 0, 0, 0);
            a1 = __builtin_amdgcn_mfma_f32_16x16x32_bf16(fih1[kb], f0, a1, 0, 0, 0);
        }
        storeL(sH0[0], a0);   // h0(1)
        storeL(sH1[0], a1);   // h1(0)
        bmPrev = bmIn;
        __syncthreads();
    }

    // ---- main: i = 2..127, one barrier per iteration ----
    auto stepMain = [&](int i, const short* r0, const short* r1,
                        short* w0b, short* w1b) {
        const bool bmIn = (sMask[i - 1] >> c) & 1u;
        const float* bp = bmIn ? (sBias + 128) : sBias;
        f32x4 a0 = *reinterpret_cast<const f32x4*>(&bp[ib]);
        f32x4 a1 = *reinterpret_cast<const f32x4*>(&sBias[256 + ib]);
        bf16x8 f0[4], f1[4];
        #pragma unroll
        for (int kb = 0; kb < 4; ++kb) {
            f0[kb] = *reinterpret_cast<const bf16x8*>(&r0[ra[kb]]);
            f1[kb] = *reinterpret_cast<const bf16x8*>(&r1[ra[kb]]);
        }
        #pragma unroll
        for (int kb = 0; kb < 4; ++kb) {
            a0 = __builtin_amdgcn_mfma_f32_16x16x32_bf16(fhh0[kb], f0[kb], a0, 0, 0, 0);
            a1 = __builtin_amdgcn_mfma_f32_16x16x32_bf16(fhh1[kb], f1[kb], a1, 0, 0, 0);
        }
        #pragma unroll
        for (int kb = 0; kb < 4; ++kb)
            a1 = __builtin_amdgcn_mfma_f32_16x16x32_bf16(fih1[kb], f0[kb], a1, 0, 0, 0);
        if (w == (i & 7)) {   // rotate logits duty across the 8 waves
            f32x4 aL = {bd0, bd1, 0.f, 0.f};
            #pragma unroll
            for (int kb = 0; kb < 4; ++kb) {
                bf16x8 fw = *reinterpret_cast<const bf16x8*>(&sFwd[(kb * 64 + lane) * 8]);
                aL = __builtin_amdgcn_mfma_f32_16x16x32_bf16(fw, f1[kb], aL, 0, 0, 0);
            }
            if (q == 0)
                sLd[(i - 2) * 17 + c] = bmPrev ? (aL[0] - aL[1]) : (aL[1] - aL[0]);
        }
        bmPrev = bmIn;
        storeL(w0b, a0);              // h0(i)
        storeL(w1b, a1);              // h1(i-1)
        __syncthreads();
    };

    for (int i = 2; i < NSTEP; i += 2) {
        stepMain(i,     sH0[0], sH1[0], sH0[1], sH1[1]);
        stepMain(i + 1, sH0[1], sH1[1], sH0[0], sH1[0]);
    }

    // ---- i = 128: h1(127), logits(126) ----
    {
        f32x4 a1 = *reinterpret_cast<const f32x4*>(&sBias[256 + ib]);
        bf16x8 f0[4], f1[4];
        #pragma unroll
        for (int kb = 0; kb < 4; ++kb) {
            f0[kb] = *reinterpret_cast<const bf16x8*>(&sH0[0][ra[kb]]);  // h0(127)
            f1[kb] = *reinterpret_cast<const bf16x8*>(&sH1[0][ra[kb]]);  // h1(126)
        }
        #pragma unroll
        for (int kb = 0; kb < 4; ++kb)
            a1 = __builtin_amdgcn_mfma_f32_16x16x32_bf16(fhh1[kb], f1[kb], a1, 0, 0, 0);
        #pragma unroll
        for (int kb = 0; kb < 4; ++kb)
            a1 = __builtin_amdgcn_mfma_f32_16x16x32_bf16(fih1[kb], f0[kb], a1, 0, 0, 0);
        if (w == 0) {
            f32x4 aL = {bd0, bd1, 0.f, 0.f};
            #pragma unroll
            for (int kb = 0; kb < 4; ++kb) {
                bf16x8 fw = *reinterpret_cast<const bf16x8*>(&sFwd[(kb * 64 + lane) * 8]);
                aL = __builtin_amdgcn_mfma_f32_16x16x32_bf16(fw, f1[kb], aL, 0, 0, 0);
            }
            if (q == 0)
                sLd[126 * 17 + c] = bmPrev ? (aL[0] - aL[1]) : (aL[1] - aL[0]);
        }
        storeL(sH1[1], a1);           // h1(127)
        __syncthreads();
    }
    // ---- i = 129: logits(127), wave 1 ----
    if (w == 1) {
        f32x4 aL = {bd0, bd1, 0.f, 0.f};
        #pragma unroll
        for (int kb = 0; kb < 4; ++kb) {
            bf16x8 f1 = *reinterpret_cast<const bf16x8*>(&sH1[1][ra[kb]]);
            bf16x8 fw = *reinterpret_cast<const bf16x8*>(&sFwd[(kb * 64 + lane) * 8]);
            aL = __builtin_amdgcn_mfma_f32_16x16x32_bf16(fw, f1, aL, 0, 0, 0);
        }
        if (q == 0) {
            const bool bit = (sMask[NSTEP - 1] >> c) & 1u;
            sLd[127 * 17 + c] = bit ? (aL[0] - aL[1]) : (aL[1] - aL[0]);
        }
    }
    __syncthreads();

    // ---- final pass: lp(s) = sum_t -log(1 + exp(diff_t)) ----
    if (tid < 256) {
        const int s = tid >> 4;       // sample 0..15
        const int k = tid & 15;       // step sub-index
        float acc = 0.0f;
        #pragma unroll
        for (int j = 0; j < 8; ++j) {
            const float x = sLd[(j * 16 + k) * 17 + s];
            const float ed = __builtin_exp2f(x * 1.4426950408889634f);
            acc -= 0.6931471805599453f * __builtin_log2f(1.0f + ed);
        }
        #pragma unroll
        for (int off = 1; off < 16; off <<= 1)
            acc += __shfl_xor(acc, off, 64);
        if (k == 0)
            out[b0 + s] = acc;
    }
}

extern "C" void kernel_launch(void* const* d_in, const int* in_sizes, int n_in,
                              void* d_out, int out_size, void* d_ws, size_t ws_size,
                              hipStream_t stream) {
    rnn_wf_kernel<<<NBLK, NTHR, 0, stream>>>(
        (const float*)d_in[0],  // samples
        (const float*)d_in[1],  // W_ih0
        (const float*)d_in[2],  // b_ih0
        (const float*)d_in[3],  // W_hh0
        (const float*)d_in[4],  // b_hh0
        (const float*)d_in[5],  // W_ih1
        (const float*)d_in[6],  // b_ih1
        (const float*)d_in[7],  // W_hh1
        (const float*)d_in[8],  // b_hh1
        (const float*)d_in[9],  // W_dense
        (const float*)d_in[10], // b_dense
        (float*)d_out);
}